// Round 4
// baseline (1136.128 us; speedup 1.0000x reference)
//
#include <hip/hip_runtime.h>
#include <math.h>

// DirectionalConv fused kernel.
// Binning pipeline emulates the numpy float32 reference BIT-EXACTLY:
//   gx,gy : f32 Sobel, strict left-to-right tap accumulation (numpy conv translation)
//   theta : glibc/fdlibm float-native atan2f (ported verbatim, no FMA contraction)
//   u     : ((theta + PI32) / (2*PI32)) * 8 in f32 (add+div round, *8 exact)
//   q     : (int)u & 7

#define TILE    16
#define XH      20      // TILE + 4 (halo 2: Sobel of the conv halo ring)
#define XPITCH  21
#define QDIM    18      // TILE + 2 (conv halo 1)
#define QPITCH  19
#define WROW    68      // 64 + 4 pad

// ---------------- fdlibm float atan (glibc s_atanf.c), bit-exact port ----------------
__device__ __forceinline__ float atanf_fdlibm(float x) {
#pragma clang fp contract(off)
    const float atanhi0 = 4.6364760399e-01f, atanhi1 = 7.8539812565e-01f,
                atanhi2 = 9.8279368877e-01f, atanhi3 = 1.5707962513e+00f;
    const float atanlo0 = 5.0121582440e-09f, atanlo1 = 3.7748947079e-08f,
                atanlo2 = 3.4473217170e-08f, atanlo3 = 7.5497894159e-08f;
    const float aT0 = 3.3333334327e-01f, aT1 = -2.0000000298e-01f, aT2 = 1.4285714924e-01f,
                aT3 = -1.1111110449e-01f, aT4 = 9.0908870101e-02f, aT5 = -7.6918758452e-02f,
                aT6 = 6.6610731184e-02f, aT7 = -5.8335702866e-02f, aT8 = 4.9768779427e-02f,
                aT9 = -3.6531571299e-02f, aT10 = 1.6285819933e-02f;

    int hx = __float_as_int(x);
    int ix = hx & 0x7fffffff;
    int id;
    if (ix >= 0x4c800000) {                 // |x| >= 2^26
        if (ix > 0x7f800000) return x + x;  // NaN
        return (hx > 0) ? (atanhi3 + atanlo3) : (-atanhi3 - atanlo3);
    }
    if (ix < 0x3ee00000) {                  // |x| < 0.4375
        if (ix < 0x31000000) return x;      // |x| < 2^-29
        id = -1;
    } else {
        x = fabsf(x);
        if (ix < 0x3f980000) {              // |x| < 1.1875
            if (ix < 0x3f300000) { id = 0; x = (2.0f * x - 1.0f) / (2.0f + x); }
            else                 { id = 1; x = (x - 1.0f) / (x + 1.0f); }
        } else {
            if (ix < 0x401c0000) { id = 2; x = (x - 1.5f) / (1.0f + 1.5f * x); }
            else                 { id = 3; x = -1.0f / x; }
        }
    }
    float z = x * x;
    float w = z * z;
    float s1 = z * (aT0 + w * (aT2 + w * (aT4 + w * (aT6 + w * (aT8 + w * aT10)))));
    float s2 = w * (aT1 + w * (aT3 + w * (aT5 + w * (aT7 + w * aT9))));
    if (id < 0) return x - x * (s1 + s2);
    float r;
    if      (id == 0) r = atanhi0 - ((x * (s1 + s2) - atanlo0) - x);
    else if (id == 1) r = atanhi1 - ((x * (s1 + s2) - atanlo1) - x);
    else if (id == 2) r = atanhi2 - ((x * (s1 + s2) - atanlo2) - x);
    else              r = atanhi3 - ((x * (s1 + s2) - atanlo3) - x);
    return (hx < 0) ? -r : r;
}

// ---------------- fdlibm float atan2 (glibc e_atan2f.c), bit-exact port ----------------
__device__ __forceinline__ float atan2f_fdlibm(float y, float x) {
#pragma clang fp contract(off)
    const float tiny = 1.0e-30f;
    const float pi_o_4 = 7.8539818525e-01f;   // 0x3f490fdb
    const float pi_o_2 = 1.5707963705e+00f;   // 0x3fc90fdb
    const float pi     = 3.1415927410e+00f;   // 0x40490fdb
    const float pi_lo  = -8.7422776573e-08f;  // 0xb3bbbd2e

    int hx = __float_as_int(x), hy = __float_as_int(y);
    int ix = hx & 0x7fffffff, iy = hy & 0x7fffffff;
    if (ix > 0x7f800000 || iy > 0x7f800000) return x + y;   // NaN
    if (hx == 0x3f800000) return atanf_fdlibm(y);           // x == 1.0
    int m = ((hy >> 31) & 1) | ((hx >> 30) & 2);

    if (iy == 0) {
        switch (m) {
            case 0:
            case 1:  return y;
            case 2:  return  pi + tiny;
            default: return -pi - tiny;
        }
    }
    if (ix == 0) return (hy < 0) ? (-pi_o_2 - tiny) : (pi_o_2 + tiny);
    if (ix == 0x7f800000) {
        if (iy == 0x7f800000) {
            switch (m) {
                case 0:  return  pi_o_4 + tiny;
                case 1:  return -pi_o_4 - tiny;
                case 2:  return  3.0f * pi_o_4 + tiny;
                default: return -3.0f * pi_o_4 - tiny;
            }
        } else {
            switch (m) {
                case 0:  return  0.0f;
                case 1:  return -0.0f;
                case 2:  return  pi + tiny;
                default: return -pi - tiny;
            }
        }
    }
    if (iy == 0x7f800000) return (hy < 0) ? (-pi_o_2 - tiny) : (pi_o_2 + tiny);

    int k = (iy - ix) >> 23;
    float z;
    int mm = m;
    if (k > 26)                    { z = pi_o_2 + 0.5f * pi_lo; mm &= 1; }
    else if (hx < 0 && k < -26)    { z = 0.0f; }
    else                           { z = atanf_fdlibm(fabsf(y / x)); }

    switch (mm) {
        case 0:  return z;
        case 1:  return -z;
        case 2:  return pi - (z - pi_lo);
        default: return (z - pi_lo) - pi;
    }
}

// bin = trunc_f32(((theta + PI32) / (2*PI32)) * 8) & 7, all f32 like numpy
__device__ __forceinline__ int bin8(float gy, float gx) {
#pragma clang fp contract(off)
    float th = atan2f_fdlibm(gy, gx);
    float t  = th + 3.14159274101257324f;    // f32 pi
    float u  = t / 6.28318548202514648f;     // f32 2*pi
    u = u * 8.0f;                            // exact
    return ((int)u) & 7;
}

__global__ __launch_bounds__(256)
void dirconv_fused(const float* __restrict__ x,
                   const float* __restrict__ Wg,
                   const float* __restrict__ bg,
                   float* __restrict__ out) {
    __shared__ float xs[XH * XPITCH];
    __shared__ int   qi[QDIM * QPITCH];
    __shared__ float wl[9 * 8 * WROW];
    __shared__ float bsum[64];

    const int tid = threadIdx.x;
    const int bb  = blockIdx.z;
    const int h0  = blockIdx.y * TILE;
    const int w0  = blockIdx.x * TILE;

    if (tid < 64) {
        float s = 0.f;
        #pragma unroll
        for (int k = 0; k < 8; ++k) s += bg[k * 64 + tid];
        bsum[tid] = s;
    }

    float acc[64];
    #pragma unroll
    for (int o = 0; o < 64; ++o) acc[o] = 0.f;

    const int pr = tid >> 4;
    const int pc = tid & 15;

    for (int c = 0; c < 64; ++c) {
        __syncthreads();   // protect LDS from previous iteration's readers

        // ---- stage x tile (20x20, zero-padded outside image) ----
        const float* xc = x + ((size_t)(bb * 64 + c) << 16);
        for (int idx = tid; idx < XH * XH; idx += 256) {
            int r  = idx / XH, cc = idx - r * XH;
            int gh = h0 + r - 2, gw = w0 + cc - 2;
            float v = 0.f;
            if ((unsigned)gh < 256u && (unsigned)gw < 256u)
                v = xc[(gh << 8) + gw];
            xs[r * XPITCH + cc] = v;
        }

        // ---- stage weight slice W[:, :, c, :, :] -> wl[tap][k][o] ----
        for (int pair = tid; pair < 512; pair += 256) {
            int k = pair >> 6, o = pair & 63;
            const float* g = Wg + ((size_t)((k << 6) + o) * 64 + c) * 9;
            #pragma unroll
            for (int tap = 0; tap < 9; ++tap)
                wl[(tap * 8 + k) * WROW + o] = g[tap];
        }
        __syncthreads();

        // ---- orientation bins on the 18x18 (tile + conv-halo) region ----
        for (int idx = tid; idx < QDIM * QDIM; idx += 256) {
#pragma clang fp contract(off)
            int r = idx / QDIM, cc = idx - r * QDIM;
            const float* p0 = &xs[r * XPITCH + cc];
            float a0 = p0[0],            a1 = p0[1],              a2 = p0[2];
            float m0 = p0[XPITCH],                                m2 = p0[XPITCH + 2];
            float z0 = p0[2 * XPITCH],   z1 = p0[2 * XPITCH + 1], z2 = p0[2 * XPITCH + 2];
            // strict left-to-right f32 tap accumulation (numpy conv order)
            float gx = ((((a0 - a2) + 2.0f * m0) - 2.0f * m2) + z0) - z2;
            float gy = ((((a0 + 2.0f * a1) + a2) - z0) - 2.0f * z1) - z2;
            qi[r * QPITCH + cc] = bin8(gy, gx);
        }
        __syncthreads();

        // ---- accumulate: 9 taps x 64 o per pixel ----
        #pragma unroll
        for (int tap = 0; tap < 9; ++tap) {
            const int di = tap / 3, dj = tap - di * 3;
            const float xv = xs[(pr + di + 1) * XPITCH + (pc + dj + 1)];
            const int   qv = qi[(pr + di) * QPITCH + (pc + dj)];
            const float4* wp = reinterpret_cast<const float4*>(&wl[(tap * 8 + qv) * WROW]);
            #pragma unroll
            for (int o4 = 0; o4 < 16; ++o4) {
                float4 w4 = wp[o4];
                acc[o4 * 4 + 0] += xv * w4.x;
                acc[o4 * 4 + 1] += xv * w4.y;
                acc[o4 * 4 + 2] += xv * w4.z;
                acc[o4 * 4 + 3] += xv * w4.w;
            }
        }
    }
    __syncthreads();

    const int ho = h0 + pr, wo = w0 + pc;
    float* op = out + ((size_t)bb << 22) + (ho << 8) + wo;
    #pragma unroll
    for (int o = 0; o < 64; ++o)
        op[(size_t)o << 16] = (acc[o] + bsum[o]) * 0.125f;
}

extern "C" void kernel_launch(void* const* d_in, const int* in_sizes, int n_in,
                              void* d_out, int out_size, void* d_ws, size_t ws_size,
                              hipStream_t stream) {
    const float* x  = (const float*)d_in[0];
    const float* Wg = (const float*)d_in[1];
    const float* bg = (const float*)d_in[2];
    float* out = (float*)d_out;

    dim3 grid(256 / TILE, 256 / TILE, 8);
    dim3 block(256);
    dirconv_fused<<<grid, block, 0, stream>>>(x, Wg, bg, out);
}

// Round 7
// 850.797 us; speedup vs baseline: 1.3354x; 1.3354x over previous
//
#include <hip/hip_runtime.h>
#include <math.h>

// DirectionalConv via masked-K MFMA GEMM.
// out[o,p] (per batch) = (1/8)( sum_{c,t,k} W[k,o,c,t] * x[c,p+dt]*[q(c,p+dt)==k] + sum_k b[k,o] )
// GEMM: M=o(64), N=pixels(512/block), K=(c 64)x(t 10 padded)x(k 8), bf16 MFMA 32x32x16.
// A = weights (LDS, XOR-swizzled 16B chunks), B = masked-x built in registers from
// packed (bf16(x)<<16|q) words. Binning is the bit-exact fdlibm f32 pipeline (unchanged).

#define TH 16
#define TW 32

typedef __attribute__((ext_vector_type(8)))  short    short8;
typedef __attribute__((ext_vector_type(16))) float    f32x16;
typedef __attribute__((ext_vector_type(4)))  unsigned u32x4;

// ---------------- fdlibm float atan (glibc s_atanf.c), bit-exact port ----------------
__device__ __forceinline__ float atanf_fdlibm(float x) {
#pragma clang fp contract(off)
    const float atanhi0 = 4.6364760399e-01f, atanhi1 = 7.8539812565e-01f,
                atanhi2 = 9.8279368877e-01f, atanhi3 = 1.5707962513e+00f;
    const float atanlo0 = 5.0121582440e-09f, atanlo1 = 3.7748947079e-08f,
                atanlo2 = 3.4473217170e-08f, atanlo3 = 7.5497894159e-08f;
    const float aT0 = 3.3333334327e-01f, aT1 = -2.0000000298e-01f, aT2 = 1.4285714924e-01f,
                aT3 = -1.1111110449e-01f, aT4 = 9.0908870101e-02f, aT5 = -7.6918758452e-02f,
                aT6 = 6.6610731184e-02f, aT7 = -5.8335702866e-02f, aT8 = 4.9768779427e-02f,
                aT9 = -3.6531571299e-02f, aT10 = 1.6285819933e-02f;

    int hx = __float_as_int(x);
    int ix = hx & 0x7fffffff;
    int id;
    if (ix >= 0x4c800000) {
        if (ix > 0x7f800000) return x + x;
        return (hx > 0) ? (atanhi3 + atanlo3) : (-atanhi3 - atanlo3);
    }
    if (ix < 0x3ee00000) {
        if (ix < 0x31000000) return x;
        id = -1;
    } else {
        x = fabsf(x);
        if (ix < 0x3f980000) {
            if (ix < 0x3f300000) { id = 0; x = (2.0f * x - 1.0f) / (2.0f + x); }
            else                 { id = 1; x = (x - 1.0f) / (x + 1.0f); }
        } else {
            if (ix < 0x401c0000) { id = 2; x = (x - 1.5f) / (1.0f + 1.5f * x); }
            else                 { id = 3; x = -1.0f / x; }
        }
    }
    float z = x * x;
    float w = z * z;
    float s1 = z * (aT0 + w * (aT2 + w * (aT4 + w * (aT6 + w * (aT8 + w * aT10)))));
    float s2 = w * (aT1 + w * (aT3 + w * (aT5 + w * (aT7 + w * aT9))));
    if (id < 0) return x - x * (s1 + s2);
    float r;
    if      (id == 0) r = atanhi0 - ((x * (s1 + s2) - atanlo0) - x);
    else if (id == 1) r = atanhi1 - ((x * (s1 + s2) - atanlo1) - x);
    else if (id == 2) r = atanhi2 - ((x * (s1 + s2) - atanlo2) - x);
    else              r = atanhi3 - ((x * (s1 + s2) - atanlo3) - x);
    return (hx < 0) ? -r : r;
}

// ---------------- fdlibm float atan2 (glibc e_atan2f.c), bit-exact port ----------------
__device__ __forceinline__ float atan2f_fdlibm(float y, float x) {
#pragma clang fp contract(off)
    const float tiny = 1.0e-30f;
    const float pi_o_4 = 7.8539818525e-01f;
    const float pi_o_2 = 1.5707963705e+00f;
    const float pi     = 3.1415927410e+00f;
    const float pi_lo  = -8.7422776573e-08f;

    int hx = __float_as_int(x), hy = __float_as_int(y);
    int ix = hx & 0x7fffffff, iy = hy & 0x7fffffff;
    if (ix > 0x7f800000 || iy > 0x7f800000) return x + y;
    if (hx == 0x3f800000) return atanf_fdlibm(y);
    int m = ((hy >> 31) & 1) | ((hx >> 30) & 2);

    if (iy == 0) {
        switch (m) {
            case 0:
            case 1:  return y;
            case 2:  return  pi + tiny;
            default: return -pi - tiny;
        }
    }
    if (ix == 0) return (hy < 0) ? (-pi_o_2 - tiny) : (pi_o_2 + tiny);
    if (ix == 0x7f800000) {
        if (iy == 0x7f800000) {
            switch (m) {
                case 0:  return  pi_o_4 + tiny;
                case 1:  return -pi_o_4 - tiny;
                case 2:  return  3.0f * pi_o_4 + tiny;
                default: return -3.0f * pi_o_4 - tiny;
            }
        } else {
            switch (m) {
                case 0:  return  0.0f;
                case 1:  return -0.0f;
                case 2:  return  pi + tiny;
                default: return -pi - tiny;
            }
        }
    }
    if (iy == 0x7f800000) return (hy < 0) ? (-pi_o_2 - tiny) : (pi_o_2 + tiny);

    int k = (iy - ix) >> 23;
    float z;
    int mm = m;
    if (k > 26)                    { z = pi_o_2 + 0.5f * pi_lo; mm &= 1; }
    else if (hx < 0 && k < -26)    { z = 0.0f; }
    else                           { z = atanf_fdlibm(fabsf(y / x)); }

    switch (mm) {
        case 0:  return z;
        case 1:  return -z;
        case 2:  return pi - (z - pi_lo);
        default: return (z - pi_lo) - pi;
    }
}

__device__ __forceinline__ int bin8(float gy, float gx) {
#pragma clang fp contract(off)
    float th = atan2f_fdlibm(gy, gx);
    float t  = th + 3.14159274101257324f;
    float u  = t / 6.28318548202514648f;
    u = u * 8.0f;
    return ((int)u) & 7;
}

__device__ __forceinline__ unsigned rne_bf16_bits(float f) {
    unsigned u = __float_as_uint(f);
    return (u + 0x7fffu + ((u >> 16) & 1u)) >> 16;
}

// ---- prep kernel: swizzle W (8,64,64,3,3) f32 -> ws[c][o][128 shorts] bf16 ----
// element (t,k) of row (c,o) stored at short index ((t ^ (o&7))<<3) + k ; chunk t=9 zeroed.
__global__ void prep_w(const float* __restrict__ Wg, short* __restrict__ wsw) {
    int tid = blockIdx.x * 256 + threadIdx.x;
    if (tid >= 4096) return;
    int c = tid >> 6, o = tid & 63;
    short* dst = wsw + (size_t)((c << 6) + o) * 128;
    int g9 = (9 ^ (o & 7)) << 3;
    #pragma unroll
    for (int e = 0; e < 8; ++e) dst[g9 + e] = 0;
    for (int k = 0; k < 8; ++k) {
        const float* g = Wg + ((size_t)((k << 6) + o) * 64 + c) * 9;
        #pragma unroll
        for (int t = 0; t < 9; ++t)
            dst[((t ^ (o & 7)) << 3) + k] = (short)rne_bf16_bits(g[t]);
    }
}

// ---- main kernel ----
template <bool USE_WS>
__global__ __launch_bounds__(256, 2)
void dirconv_mfma(const float* __restrict__ x,
                  const float* __restrict__ Wg,
                  const short* __restrict__ wsw,
                  const float* __restrict__ bg,
                  float* __restrict__ out) {
    __shared__ float    xs[20 * 37];
    __shared__ unsigned pw[18 * 36];
    __shared__ short    wl[64][128];     // 16 KB, rows 256B, 16B chunks XOR-swizzled
    __shared__ float    bsum[64];

    const int tid  = threadIdx.x;
    const int wave = tid >> 6;
    const int lane = tid & 63;
    const int h    = lane >> 5;     // K-half
    const int l31  = lane & 31;
    const int bb   = blockIdx.z;
    const int h0   = blockIdx.y * TH;
    const int w0   = blockIdx.x * TW;

    if (tid < 64) {
        float s = 0.f;
        #pragma unroll
        for (int k = 0; k < 8; ++k) s += bg[k * 64 + tid];
        bsum[tid] = s;
    }

    f32x16 acc[2][4];   // [mf][nf]
    #pragma unroll
    for (int i = 0; i < 2; ++i)
        #pragma unroll
        for (int j = 0; j < 4; ++j)
            acc[i][j] = (f32x16)0.f;

    const int swz0 = l31 & 7;          // same for o = l31 and o = 32+l31

    for (int c = 0; c < 64; ++c) {
        __syncthreads();   // protect LDS from previous iteration's readers

        // ---- phase 1: stage x tile (20x36) and weight slice ----
        const float* xc = x + ((size_t)(bb * 64 + c) << 16);
        for (int idx = tid; idx < 720; idx += 256) {
            int r = idx / 36, cc = idx - r * 36;
            int gh = h0 + r - 2, gw = w0 + cc - 2;
            float v = 0.f;
            if ((unsigned)gh < 256u && (unsigned)gw < 256u)
                v = xc[(gh << 8) + gw];
            xs[r * 37 + cc] = v;
        }
        if (USE_WS) {
            const u32x4* src = (const u32x4*)(wsw + (size_t)c * 8192);
            u32x4* dst = (u32x4*)&wl[0][0];
            #pragma unroll
            for (int i = 0; i < 4; ++i)
                dst[tid * 4 + i] = src[tid * 4 + i];
        } else {
            for (int pair = tid; pair < 512; pair += 256) {
                int k = pair >> 6, o = pair & 63;
                const float* g = Wg + ((size_t)((k << 6) + o) * 64 + c) * 9;
                #pragma unroll
                for (int t = 0; t < 9; ++t)
                    wl[o][((t ^ (o & 7)) << 3) + k] = (short)rne_bf16_bits(g[t]);
            }
            if (tid < 64) {
                int o = tid;
                #pragma unroll
                for (int e = 0; e < 8; ++e) wl[o][((9 ^ (o & 7)) << 3) + e] = 0;
            }
        }
        __syncthreads();

        // ---- phase 2: packed (bf16(x)<<16 | q) on 18x34 region ----
        for (int idx = tid; idx < 612; idx += 256) {
            int r = idx / 34, cc = idx - r * 34;
            const float* p0 = &xs[r * 37 + cc];
            int q;
            unsigned hv;
            {
#pragma clang fp contract(off)
                float a0 = p0[0],  a1 = p0[1],  a2 = p0[2];
                float m0 = p0[37],              m2 = p0[39];
                float z0 = p0[74], z1 = p0[75], z2 = p0[76];
                float gx = ((((a0 - a2) + 2.0f * m0) - 2.0f * m2) + z0) - z2;
                float gy = ((((a0 + 2.0f * a1) + a2) - z0) - 2.0f * z1) - z2;
                q  = bin8(gy, gx);
                hv = rne_bf16_bits(p0[38]);
            }
            pw[r * 36 + cc] = (hv << 16) | (unsigned)q;
        }
        __syncthreads();

        // ---- phase 3: MFMA over K = 80 (10 taps x 8 bins) ----
        #pragma unroll
        for (int s = 0; s < 5; ++s) {
            const int t = 2 * s + h;                    // per-lane tap (t==9 is pad)
            short8 a0 = *(const short8*)&wl[l31     ][(t ^ swz0) << 3];
            short8 a1 = *(const short8*)&wl[32 + l31][(t ^ swz0) << 3];

            const int t3 = t / 3;
            const int dy = t3 - 1, dx = t - t3 * 3 - 1;
            const bool val = (t <= 8);

            #pragma unroll
            for (int nf = 0; nf < 4; ++nf) {
                int py = wave * 4 + nf;
                int rr = val ? (py + 1 + dy) : 0;
                int c2 = val ? (l31 + 1 + dx) : 0;
                unsigned pv = pw[rr * 36 + c2];
                pv = val ? pv : 0u;
                unsigned q   = pv & 7u;
                unsigned hhi = pv & 0xffff0000u;
                unsigned hlo = pv >> 16;
                u32x4 bw;
                bw.x = (q == 0u ? hlo : 0u) | (q == 1u ? hhi : 0u);
                bw.y = (q == 2u ? hlo : 0u) | (q == 3u ? hhi : 0u);
                bw.z = (q == 4u ? hlo : 0u) | (q == 5u ? hhi : 0u);
                bw.w = (q == 6u ? hlo : 0u) | (q == 7u ? hhi : 0u);
                short8 bf = __builtin_bit_cast(short8, bw);
                acc[0][nf] = __builtin_amdgcn_mfma_f32_32x32x16_bf16(a0, bf, acc[0][nf], 0, 0, 0);
                acc[1][nf] = __builtin_amdgcn_mfma_f32_32x32x16_bf16(a1, bf, acc[1][nf], 0, 0, 0);
            }
        }
    }

    // ---- epilogue: C/D layout col=lane&31 (pixel), row=(reg&3)+8*(reg>>2)+4*(lane>>5) (o) ----
    float* ob = out + ((size_t)bb << 22);
    #pragma unroll
    for (int mf = 0; mf < 2; ++mf)
        #pragma unroll
        for (int nf = 0; nf < 4; ++nf) {
            int py = wave * 4 + nf;
            #pragma unroll
            for (int reg = 0; reg < 16; ++reg) {
                int o = mf * 32 + (reg & 3) + 8 * (reg >> 2) + 4 * h;
                ob[((size_t)o << 16) + ((h0 + py) << 8) + (w0 + l31)] =
                    (acc[mf][nf][reg] + bsum[o]) * 0.125f;
            }
        }
}

extern "C" void kernel_launch(void* const* d_in, const int* in_sizes, int n_in,
                              void* d_out, int out_size, void* d_ws, size_t ws_size,
                              hipStream_t stream) {
    const float* x  = (const float*)d_in[0];
    const float* Wg = (const float*)d_in[1];
    const float* bg = (const float*)d_in[2];
    float* out = (float*)d_out;

    dim3 grid(256 / TW, 256 / TH, 8);   // (8, 16, 8) = 1024 blocks
    dim3 block(256);

    const size_t need = (size_t)64 * 64 * 128 * sizeof(short);  // 1 MB
    if (ws_size >= need) {
        short* wsw = (short*)d_ws;
        prep_w<<<16, 256, 0, stream>>>(Wg, wsw);
        dirconv_mfma<true><<<grid, block, 0, stream>>>(x, Wg, wsw, bg, out);
    } else {
        dirconv_mfma<false><<<grid, block, 0, stream>>>(x, Wg, nullptr, bg, out);
    }
}

// Round 8
// 445.669 us; speedup vs baseline: 2.5493x; 1.9090x over previous
//
#include <hip/hip_runtime.h>
#include <math.h>

// DirectionalConv, two-stage:
//   bin_kernel: per-pixel packed (bf16(x)<<16 | q) with bit-exact fdlibm f32 binning -> d_ws
//   dirconv_mfma2: masked-K MFMA GEMM; per-pixel one-hot expanded once into LDS (u32x4),
//                  MFMA loop is pure ds_read_b128 -> mfma. Double-buffered, 1 barrier/c.
// Fallback (small ws): R7 fused kernel (proven).

#define TH 16
#define TW 32

typedef __attribute__((ext_vector_type(8)))  short    short8;
typedef __attribute__((ext_vector_type(16))) float    f32x16;
typedef __attribute__((ext_vector_type(4)))  unsigned u32x4;

// ---------------- fdlibm float atan (glibc s_atanf.c), bit-exact port ----------------
__device__ __forceinline__ float atanf_fdlibm(float x) {
#pragma clang fp contract(off)
    const float atanhi0 = 4.6364760399e-01f, atanhi1 = 7.8539812565e-01f,
                atanhi2 = 9.8279368877e-01f, atanhi3 = 1.5707962513e+00f;
    const float atanlo0 = 5.0121582440e-09f, atanlo1 = 3.7748947079e-08f,
                atanlo2 = 3.4473217170e-08f, atanlo3 = 7.5497894159e-08f;
    const float aT0 = 3.3333334327e-01f, aT1 = -2.0000000298e-01f, aT2 = 1.4285714924e-01f,
                aT3 = -1.1111110449e-01f, aT4 = 9.0908870101e-02f, aT5 = -7.6918758452e-02f,
                aT6 = 6.6610731184e-02f, aT7 = -5.8335702866e-02f, aT8 = 4.9768779427e-02f,
                aT9 = -3.6531571299e-02f, aT10 = 1.6285819933e-02f;

    int hx = __float_as_int(x);
    int ix = hx & 0x7fffffff;
    int id;
    if (ix >= 0x4c800000) {
        if (ix > 0x7f800000) return x + x;
        return (hx > 0) ? (atanhi3 + atanlo3) : (-atanhi3 - atanlo3);
    }
    if (ix < 0x3ee00000) {
        if (ix < 0x31000000) return x;
        id = -1;
    } else {
        x = fabsf(x);
        if (ix < 0x3f980000) {
            if (ix < 0x3f300000) { id = 0; x = (2.0f * x - 1.0f) / (2.0f + x); }
            else                 { id = 1; x = (x - 1.0f) / (x + 1.0f); }
        } else {
            if (ix < 0x401c0000) { id = 2; x = (x - 1.5f) / (1.0f + 1.5f * x); }
            else                 { id = 3; x = -1.0f / x; }
        }
    }
    float z = x * x;
    float w = z * z;
    float s1 = z * (aT0 + w * (aT2 + w * (aT4 + w * (aT6 + w * (aT8 + w * aT10)))));
    float s2 = w * (aT1 + w * (aT3 + w * (aT5 + w * (aT7 + w * aT9))));
    if (id < 0) return x - x * (s1 + s2);
    float r;
    if      (id == 0) r = atanhi0 - ((x * (s1 + s2) - atanlo0) - x);
    else if (id == 1) r = atanhi1 - ((x * (s1 + s2) - atanlo1) - x);
    else if (id == 2) r = atanhi2 - ((x * (s1 + s2) - atanlo2) - x);
    else              r = atanhi3 - ((x * (s1 + s2) - atanlo3) - x);
    return (hx < 0) ? -r : r;
}

// ---------------- fdlibm float atan2 (glibc e_atan2f.c), bit-exact port ----------------
__device__ __forceinline__ float atan2f_fdlibm(float y, float x) {
#pragma clang fp contract(off)
    const float tiny = 1.0e-30f;
    const float pi_o_4 = 7.8539818525e-01f;
    const float pi_o_2 = 1.5707963705e+00f;
    const float pi     = 3.1415927410e+00f;
    const float pi_lo  = -8.7422776573e-08f;

    int hx = __float_as_int(x), hy = __float_as_int(y);
    int ix = hx & 0x7fffffff, iy = hy & 0x7fffffff;
    if (ix > 0x7f800000 || iy > 0x7f800000) return x + y;
    if (hx == 0x3f800000) return atanf_fdlibm(y);
    int m = ((hy >> 31) & 1) | ((hx >> 30) & 2);

    if (iy == 0) {
        switch (m) {
            case 0:
            case 1:  return y;
            case 2:  return  pi + tiny;
            default: return -pi - tiny;
        }
    }
    if (ix == 0) return (hy < 0) ? (-pi_o_2 - tiny) : (pi_o_2 + tiny);
    if (ix == 0x7f800000) {
        if (iy == 0x7f800000) {
            switch (m) {
                case 0:  return  pi_o_4 + tiny;
                case 1:  return -pi_o_4 - tiny;
                case 2:  return  3.0f * pi_o_4 + tiny;
                default: return -3.0f * pi_o_4 - tiny;
            }
        } else {
            switch (m) {
                case 0:  return  0.0f;
                case 1:  return -0.0f;
                case 2:  return  pi + tiny;
                default: return -pi - tiny;
            }
        }
    }
    if (iy == 0x7f800000) return (hy < 0) ? (-pi_o_2 - tiny) : (pi_o_2 + tiny);

    int k = (iy - ix) >> 23;
    float z;
    int mm = m;
    if (k > 26)                    { z = pi_o_2 + 0.5f * pi_lo; mm &= 1; }
    else if (hx < 0 && k < -26)    { z = 0.0f; }
    else                           { z = atanf_fdlibm(fabsf(y / x)); }

    switch (mm) {
        case 0:  return z;
        case 1:  return -z;
        case 2:  return pi - (z - pi_lo);
        default: return (z - pi_lo) - pi;
    }
}

__device__ __forceinline__ int bin8(float gy, float gx) {
#pragma clang fp contract(off)
    float th = atan2f_fdlibm(gy, gx);
    float t  = th + 3.14159274101257324f;
    float u  = t / 6.28318548202514648f;
    u = u * 8.0f;
    return ((int)u) & 7;
}

__device__ __forceinline__ unsigned rne_bf16_bits(float f) {
    unsigned u = __float_as_uint(f);
    return (u + 0x7fffu + ((u >> 16) & 1u)) >> 16;
}

// ================= stage 1: per-pixel bins =================
__global__ __launch_bounds__(256)
void bin_kernel(const float* __restrict__ x, unsigned* __restrict__ pwg) {
    __shared__ float rs[3][260];
    const int w    = threadIdx.x;
    const int hrow = blockIdx.x;
    const int img  = blockIdx.y;    // b*64 + c
    const float* xim = x + ((size_t)img << 16);
    #pragma unroll
    for (int r = 0; r < 3; ++r) {
        int gh = hrow - 1 + r;
        float v = 0.f;
        if ((unsigned)gh < 256u) v = xim[(gh << 8) + w];
        rs[r][w + 1] = v;
        if (w == 0) { rs[r][0] = 0.f; rs[r][257] = 0.f; }
    }
    __syncthreads();
    int q; unsigned hv;
    {
#pragma clang fp contract(off)
        float a0 = rs[0][w], a1 = rs[0][w + 1], a2 = rs[0][w + 2];
        float m0 = rs[1][w],                    m2 = rs[1][w + 2];
        float z0 = rs[2][w], z1 = rs[2][w + 1], z2 = rs[2][w + 2];
        float gx = ((((a0 - a2) + 2.0f * m0) - 2.0f * m2) + z0) - z2;
        float gy = ((((a0 + 2.0f * a1) + a2) - z0) - 2.0f * z1) - z2;
        q  = bin8(gy, gx);
        hv = rne_bf16_bits(rs[1][w + 1]);
    }
    pwg[((size_t)img << 16) + (hrow << 8) + w] = (hv << 16) | (unsigned)q;
}

// ================= stage 1b: weights -> [c][t10][o64][k8] bf16 =================
__global__ void prep_w2(const float* __restrict__ Wg, short* __restrict__ wsw) {
    int tid = blockIdx.x * 256 + threadIdx.x;
    if (tid >= 4096) return;
    int c = tid >> 6, o = tid & 63;
    for (int t = 0; t < 9; ++t)
        #pragma unroll
        for (int k = 0; k < 8; ++k)
            wsw[((((c * 10 + t) << 6) + o) << 3) + k] =
                (short)rne_bf16_bits(Wg[(((k << 6) + o) * 64 + c) * 9 + t]);
    #pragma unroll
    for (int k = 0; k < 8; ++k)
        wsw[((((c * 10 + 9) << 6) + o) << 3) + k] = 0;
}

// one-hot expansion of packed (bf16<<16|q) into 8 bf16 K-slots (4 words)
__device__ __forceinline__ void build_oh(unsigned pv, u32x4* dst) {
    unsigned q  = pv & 7u;
    unsigned hv = (q & 1u) ? (pv & 0xffff0000u) : (pv >> 16);
    unsigned s2 = q >> 1;
    u32x4 oh;
    oh.x = (s2 == 0u) ? hv : 0u;
    oh.y = (s2 == 1u) ? hv : 0u;
    oh.z = (s2 == 2u) ? hv : 0u;
    oh.w = (s2 == 3u) ? hv : 0u;
    *dst = oh;
}

// ================= stage 2: MFMA GEMM =================
__global__ __launch_bounds__(256, 2)
void dirconv_mfma2(const unsigned* __restrict__ pwg,
                   const short*    __restrict__ wsw,
                   const float*    __restrict__ bg,
                   float*          __restrict__ out) {
    __shared__ u32x4 pwx[2][648];   // 18 rows x 36 pitch (34 used): per-pixel one-hot
    __shared__ u32x4 wl2[2][640];   // [t10][o64]: A fragments, lane-contiguous
    __shared__ float bsum[64];

    const int tid  = threadIdx.x;
    const int wave = tid >> 6;
    const int lane = tid & 63;
    const int h    = lane >> 5;
    const int l31  = lane & 31;
    const int bb   = blockIdx.z;
    const int h0   = blockIdx.y * TH;
    const int w0c  = blockIdx.x * TW;

    if (tid < 64) {
        float s = 0.f;
        #pragma unroll
        for (int k = 0; k < 8; ++k) s += bg[k * 64 + tid];
        bsum[tid] = s;
    }

    f32x16 acc[2][4];
    #pragma unroll
    for (int i = 0; i < 2; ++i)
        #pragma unroll
        for (int j = 0; j < 4; ++j)
            acc[i][j] = (f32x16)0.f;

    // per-lane tap geometry (s compile-time, h runtime); t=9 pad -> A=0, read clamped
    int rro[5], c2o[5];
    #pragma unroll
    for (int s = 0; s < 5; ++s) {
        int t = 2 * s + h;
        int t3 = t / 3;
        rro[s] = (t <= 8) ? t3 : 0;            // = 1 + dy
        c2o[s] = (t <= 8) ? (t - t3 * 3) : 0;  // = 1 + dx
    }

    // ---- prologue: stage c = 0 into buffer 0 ----
    {
        const u32x4* wsrc = (const u32x4*)wsw;
        wl2[0][tid]       = wsrc[tid];
        wl2[0][tid + 256] = wsrc[tid + 256];
        if (tid < 128) wl2[0][tid + 512] = wsrc[tid + 512];
        const unsigned* pimg = pwg + ((size_t)(bb * 64) << 16);
        #pragma unroll
        for (int rd = 0; rd < 3; ++rd) {
            int idx = tid + rd * 256;
            if (idx < 612) {
                int r = idx / 34, cc2 = idx - r * 34;
                int gh = h0 + r - 1, gw = w0c + cc2 - 1;
                unsigned pv = 0;
                if ((unsigned)gh < 256u && (unsigned)gw < 256u)
                    pv = pimg[(gh << 8) + gw];
                build_oh(pv, &pwx[0][r * 36 + cc2]);
            }
        }
    }
    __syncthreads();

    #pragma unroll 2
    for (int c = 0; c < 64; ++c) {
        const int cb = c & 1, nb = cb ^ 1;
        u32x4 wv0 = (u32x4)0u, wv1 = (u32x4)0u, wv2 = (u32x4)0u;
        unsigned pv0 = 0, pv1 = 0, pv2 = 0;

        if (c < 63) {   // issue next-channel loads early (hide under MFMA)
            const u32x4* wsrc = (const u32x4*)(wsw + (size_t)(c + 1) * 5120);
            wv0 = wsrc[tid];
            wv1 = wsrc[tid + 256];
            if (tid < 128) wv2 = wsrc[tid + 512];
            const unsigned* pimg = pwg + ((size_t)(bb * 64 + c + 1) << 16);
            {   int idx = tid;       int r = idx / 34, cc2 = idx - r * 34;
                int gh = h0 + r - 1, gw = w0c + cc2 - 1;
                if ((unsigned)gh < 256u && (unsigned)gw < 256u) pv0 = pimg[(gh << 8) + gw]; }
            {   int idx = tid + 256; int r = idx / 34, cc2 = idx - r * 34;
                int gh = h0 + r - 1, gw = w0c + cc2 - 1;
                if ((unsigned)gh < 256u && (unsigned)gw < 256u) pv1 = pimg[(gh << 8) + gw]; }
            if (tid < 100) {
                int idx = tid + 512; int r = idx / 34, cc2 = idx - r * 34;
                int gh = h0 + r - 1, gw = w0c + cc2 - 1;
                if ((unsigned)gh < 256u && (unsigned)gw < 256u) pv2 = pimg[(gh << 8) + gw]; }
        }

        // ---- MFMA from buffer cb: 40 MFMAs, pure ds_read_b128 + mfma ----
        {
            const u32x4* pb = &pwx[cb][0];
            const u32x4* wb = &wl2[cb][0];
            #pragma unroll
            for (int s = 0; s < 5; ++s) {
                const int t = 2 * s + h;
                short8 a0 = __builtin_bit_cast(short8, wb[t * 64 + l31]);
                short8 a1 = __builtin_bit_cast(short8, wb[t * 64 + 32 + l31]);
                #pragma unroll
                for (int nf = 0; nf < 4; ++nf) {
                    int py = wave * 4 + nf;
                    short8 bf = __builtin_bit_cast(short8,
                                    pb[(py + rro[s]) * 36 + l31 + c2o[s]]);
                    acc[0][nf] = __builtin_amdgcn_mfma_f32_32x32x16_bf16(a0, bf, acc[0][nf], 0, 0, 0);
                    acc[1][nf] = __builtin_amdgcn_mfma_f32_32x32x16_bf16(a1, bf, acc[1][nf], 0, 0, 0);
                }
            }
        }

        // ---- write staged c+1 into buffer nb ----
        if (c < 63) {
            wl2[nb][tid]       = wv0;
            wl2[nb][tid + 256] = wv1;
            if (tid < 128) wl2[nb][tid + 512] = wv2;
            {   int idx = tid;       int r = idx / 34, cc2 = idx - r * 34;
                build_oh(pv0, &pwx[nb][r * 36 + cc2]); }
            {   int idx = tid + 256; int r = idx / 34, cc2 = idx - r * 34;
                build_oh(pv1, &pwx[nb][r * 36 + cc2]); }
            if (tid < 100) {
                int idx = tid + 512; int r = idx / 34, cc2 = idx - r * 34;
                build_oh(pv2, &pwx[nb][r * 36 + cc2]); }
        }
        __syncthreads();
    }

    // ---- epilogue: C/D layout col=lane&31 (pixel), row=(reg&3)+8*(reg>>2)+4*(lane>>5) (o) ----
    float* ob = out + ((size_t)bb << 22);
    #pragma unroll
    for (int mf = 0; mf < 2; ++mf)
        #pragma unroll
        for (int nf = 0; nf < 4; ++nf) {
            int py = wave * 4 + nf;
            #pragma unroll
            for (int reg = 0; reg < 16; ++reg) {
                int o = mf * 32 + (reg & 3) + 8 * (reg >> 2) + 4 * h;
                ob[((size_t)o << 16) + ((h0 + py) << 8) + (w0c + l31)] =
                    (acc[mf][nf][reg] + bsum[o]) * 0.125f;
            }
        }
}

// ================= fallback: R7 fused kernel (proven PASS @850us) =================
__global__ __launch_bounds__(256, 2)
void dirconv_fb(const float* __restrict__ x,
                const float* __restrict__ Wg,
                const float* __restrict__ bg,
                float* __restrict__ out) {
    __shared__ float    xs[20 * 37];
    __shared__ unsigned pw[18 * 36];
    __shared__ short    wl[64][128];
    __shared__ float    bsum[64];

    const int tid  = threadIdx.x;
    const int wave = tid >> 6;
    const int lane = tid & 63;
    const int h    = lane >> 5;
    const int l31  = lane & 31;
    const int bb   = blockIdx.z;
    const int h0   = blockIdx.y * TH;
    const int w0   = blockIdx.x * TW;

    if (tid < 64) {
        float s = 0.f;
        #pragma unroll
        for (int k = 0; k < 8; ++k) s += bg[k * 64 + tid];
        bsum[tid] = s;
    }

    f32x16 acc[2][4];
    #pragma unroll
    for (int i = 0; i < 2; ++i)
        #pragma unroll
        for (int j = 0; j < 4; ++j)
            acc[i][j] = (f32x16)0.f;

    const int swz0 = l31 & 7;

    for (int c = 0; c < 64; ++c) {
        __syncthreads();
        const float* xc = x + ((size_t)(bb * 64 + c) << 16);
        for (int idx = tid; idx < 720; idx += 256) {
            int r = idx / 36, cc = idx - r * 36;
            int gh = h0 + r - 2, gw = w0 + cc - 2;
            float v = 0.f;
            if ((unsigned)gh < 256u && (unsigned)gw < 256u)
                v = xc[(gh << 8) + gw];
            xs[r * 37 + cc] = v;
        }
        for (int pair = tid; pair < 512; pair += 256) {
            int k = pair >> 6, o = pair & 63;
            const float* g = Wg + ((size_t)((k << 6) + o) * 64 + c) * 9;
            #pragma unroll
            for (int t = 0; t < 9; ++t)
                wl[o][((t ^ (o & 7)) << 3) + k] = (short)rne_bf16_bits(g[t]);
        }
        if (tid < 64) {
            int o = tid;
            #pragma unroll
            for (int e = 0; e < 8; ++e) wl[o][((9 ^ (o & 7)) << 3) + e] = 0;
        }
        __syncthreads();

        for (int idx = tid; idx < 612; idx += 256) {
            int r = idx / 34, cc = idx - r * 34;
            const float* p0 = &xs[r * 37 + cc];
            int q; unsigned hv;
            {
#pragma clang fp contract(off)
                float a0 = p0[0],  a1 = p0[1],  a2 = p0[2];
                float m0 = p0[37],              m2 = p0[39];
                float z0 = p0[74], z1 = p0[75], z2 = p0[76];
                float gx = ((((a0 - a2) + 2.0f * m0) - 2.0f * m2) + z0) - z2;
                float gy = ((((a0 + 2.0f * a1) + a2) - z0) - 2.0f * z1) - z2;
                q  = bin8(gy, gx);
                hv = rne_bf16_bits(p0[38]);
            }
            pw[r * 36 + cc] = (hv << 16) | (unsigned)q;
        }
        __syncthreads();

        #pragma unroll
        for (int s = 0; s < 5; ++s) {
            const int t = 2 * s + h;
            short8 a0 = *(const short8*)&wl[l31     ][(t ^ swz0) << 3];
            short8 a1 = *(const short8*)&wl[32 + l31][(t ^ swz0) << 3];
            const int t3 = t / 3;
            const int dy = t3 - 1, dx = t - t3 * 3 - 1;
            const bool val = (t <= 8);
            #pragma unroll
            for (int nf = 0; nf < 4; ++nf) {
                int py = wave * 4 + nf;
                int rr = val ? (py + 1 + dy) : 0;
                int c2 = val ? (l31 + 1 + dx) : 0;
                unsigned pv = pw[rr * 36 + c2];
                pv = val ? pv : 0u;
                unsigned q   = pv & 7u;
                unsigned hhi = pv & 0xffff0000u;
                unsigned hlo = pv >> 16;
                u32x4 bw;
                bw.x = (q == 0u ? hlo : 0u) | (q == 1u ? hhi : 0u);
                bw.y = (q == 2u ? hlo : 0u) | (q == 3u ? hhi : 0u);
                bw.z = (q == 4u ? hlo : 0u) | (q == 5u ? hhi : 0u);
                bw.w = (q == 6u ? hlo : 0u) | (q == 7u ? hhi : 0u);
                short8 bf = __builtin_bit_cast(short8, bw);
                acc[0][nf] = __builtin_amdgcn_mfma_f32_32x32x16_bf16(a0, bf, acc[0][nf], 0, 0, 0);
                acc[1][nf] = __builtin_amdgcn_mfma_f32_32x32x16_bf16(a1, bf, acc[1][nf], 0, 0, 0);
            }
        }
    }

    float* ob = out + ((size_t)bb << 22);
    #pragma unroll
    for (int mf = 0; mf < 2; ++mf)
        #pragma unroll
        for (int nf = 0; nf < 4; ++nf) {
            int py = wave * 4 + nf;
            #pragma unroll
            for (int reg = 0; reg < 16; ++reg) {
                int o = mf * 32 + (reg & 3) + 8 * (reg >> 2) + 4 * h;
                ob[((size_t)o << 16) + ((h0 + py) << 8) + (w0 + l31)] =
                    (acc[mf][nf][reg] + bsum[o]) * 0.125f;
            }
        }
}

extern "C" void kernel_launch(void* const* d_in, const int* in_sizes, int n_in,
                              void* d_out, int out_size, void* d_ws, size_t ws_size,
                              hipStream_t stream) {
    const float* x  = (const float*)d_in[0];
    const float* Wg = (const float*)d_in[1];
    const float* bg = (const float*)d_in[2];
    float* out = (float*)d_out;

    dim3 grid(256 / TW, 256 / TH, 8);   // (8, 16, 8) = 1024 blocks
    dim3 block(256);

    const size_t pw_bytes   = (size_t)8 * 64 * 256 * 256 * 4;   // 134,217,728
    const size_t wsw2_bytes = (size_t)64 * 10 * 64 * 8 * 2;     // 655,360

    if (ws_size >= pw_bytes + wsw2_bytes) {
        unsigned* pwg = (unsigned*)d_ws;
        short*    wsw = (short*)((char*)d_ws + pw_bytes);
        bin_kernel<<<dim3(256, 512, 1), 256, 0, stream>>>(x, pwg);
        prep_w2<<<16, 256, 0, stream>>>(Wg, wsw);
        dirconv_mfma2<<<grid, block, 0, stream>>>(pwg, wsw, bg, out);
    } else {
        dirconv_fb<<<grid, block, 0, stream>>>(x, Wg, bg, out);
    }
}

// Round 9
// 416.015 us; speedup vs baseline: 2.7310x; 1.0713x over previous
//
#include <hip/hip_runtime.h>
#include <math.h>

// DirectionalConv, two-stage:
//   bin_kernel: per-pixel packed (bf16(x)<<16 | q), branch-free bit-exact fdlibm f32 binning
//   dirconv_mfma2: masked-K MFMA GEMM, staging interleaved between MFMA clusters + setprio
// Fallback (small ws): R7 fused kernel with branchy fdlibm (proven).

#define TH 16
#define TW 32

typedef __attribute__((ext_vector_type(8)))  short    short8;
typedef __attribute__((ext_vector_type(16))) float    f32x16;
typedef __attribute__((ext_vector_type(4)))  unsigned u32x4;

// ---------------- fdlibm float atan (glibc s_atanf.c), bit-exact port (branchy) ----------------
__device__ __forceinline__ float atanf_fdlibm(float x) {
#pragma clang fp contract(off)
    const float atanhi0 = 4.6364760399e-01f, atanhi1 = 7.8539812565e-01f,
                atanhi2 = 9.8279368877e-01f, atanhi3 = 1.5707962513e+00f;
    const float atanlo0 = 5.0121582440e-09f, atanlo1 = 3.7748947079e-08f,
                atanlo2 = 3.4473217170e-08f, atanlo3 = 7.5497894159e-08f;
    const float aT0 = 3.3333334327e-01f, aT1 = -2.0000000298e-01f, aT2 = 1.4285714924e-01f,
                aT3 = -1.1111110449e-01f, aT4 = 9.0908870101e-02f, aT5 = -7.6918758452e-02f,
                aT6 = 6.6610731184e-02f, aT7 = -5.8335702866e-02f, aT8 = 4.9768779427e-02f,
                aT9 = -3.6531571299e-02f, aT10 = 1.6285819933e-02f;

    int hx = __float_as_int(x);
    int ix = hx & 0x7fffffff;
    int id;
    if (ix >= 0x4c800000) {
        if (ix > 0x7f800000) return x + x;
        return (hx > 0) ? (atanhi3 + atanlo3) : (-atanhi3 - atanlo3);
    }
    if (ix < 0x3ee00000) {
        if (ix < 0x31000000) return x;
        id = -1;
    } else {
        x = fabsf(x);
        if (ix < 0x3f980000) {
            if (ix < 0x3f300000) { id = 0; x = (2.0f * x - 1.0f) / (2.0f + x); }
            else                 { id = 1; x = (x - 1.0f) / (x + 1.0f); }
        } else {
            if (ix < 0x401c0000) { id = 2; x = (x - 1.5f) / (1.0f + 1.5f * x); }
            else                 { id = 3; x = -1.0f / x; }
        }
    }
    float z = x * x;
    float w = z * z;
    float s1 = z * (aT0 + w * (aT2 + w * (aT4 + w * (aT6 + w * (aT8 + w * aT10)))));
    float s2 = w * (aT1 + w * (aT3 + w * (aT5 + w * (aT7 + w * aT9))));
    if (id < 0) return x - x * (s1 + s2);
    float r;
    if      (id == 0) r = atanhi0 - ((x * (s1 + s2) - atanlo0) - x);
    else if (id == 1) r = atanhi1 - ((x * (s1 + s2) - atanlo1) - x);
    else if (id == 2) r = atanhi2 - ((x * (s1 + s2) - atanlo2) - x);
    else              r = atanhi3 - ((x * (s1 + s2) - atanlo3) - x);
    return (hx < 0) ? -r : r;
}

// ---------------- fdlibm float atan2 (glibc e_atan2f.c), bit-exact port (branchy) ----------------
__device__ __forceinline__ float atan2f_fdlibm(float y, float x) {
#pragma clang fp contract(off)
    const float tiny = 1.0e-30f;
    const float pi_o_4 = 7.8539818525e-01f;
    const float pi_o_2 = 1.5707963705e+00f;
    const float pi     = 3.1415927410e+00f;
    const float pi_lo  = -8.7422776573e-08f;

    int hx = __float_as_int(x), hy = __float_as_int(y);
    int ix = hx & 0x7fffffff, iy = hy & 0x7fffffff;
    if (ix > 0x7f800000 || iy > 0x7f800000) return x + y;
    if (hx == 0x3f800000) return atanf_fdlibm(y);
    int m = ((hy >> 31) & 1) | ((hx >> 30) & 2);

    if (iy == 0) {
        switch (m) {
            case 0:
            case 1:  return y;
            case 2:  return  pi + tiny;
            default: return -pi - tiny;
        }
    }
    if (ix == 0) return (hy < 0) ? (-pi_o_2 - tiny) : (pi_o_2 + tiny);
    if (ix == 0x7f800000) {
        if (iy == 0x7f800000) {
            switch (m) {
                case 0:  return  pi_o_4 + tiny;
                case 1:  return -pi_o_4 - tiny;
                case 2:  return  3.0f * pi_o_4 + tiny;
                default: return -3.0f * pi_o_4 - tiny;
            }
        } else {
            switch (m) {
                case 0:  return  0.0f;
                case 1:  return -0.0f;
                case 2:  return  pi + tiny;
                default: return -pi - tiny;
            }
        }
    }
    if (iy == 0x7f800000) return (hy < 0) ? (-pi_o_2 - tiny) : (pi_o_2 + tiny);

    int k = (iy - ix) >> 23;
    float z;
    int mm = m;
    if (k > 26)                    { z = pi_o_2 + 0.5f * pi_lo; mm &= 1; }
    else if (hx < 0 && k < -26)    { z = 0.0f; }
    else                           { z = atanf_fdlibm(fabsf(y / x)); }

    switch (mm) {
        case 0:  return z;
        case 1:  return -z;
        case 2:  return pi - (z - pi_lo);
        default: return (z - pi_lo) - pi;
    }
}

__device__ __forceinline__ int bin8(float gy, float gx) {
#pragma clang fp contract(off)
    float th = atan2f_fdlibm(gy, gx);
    float t  = th + 3.14159274101257324f;
    float u  = t / 6.28318548202514648f;
    u = u * 8.0f;
    return ((int)u) & 7;
}

// ---------------- branch-free bit-exact bin (select-chains, one division in atan core) ----------
__device__ __forceinline__ int bin8_bf(float gy, float gx) {
#pragma clang fp contract(off)
    const float aT0 = 3.3333334327e-01f, aT1 = -2.0000000298e-01f, aT2 = 1.4285714924e-01f,
                aT3 = -1.1111110449e-01f, aT4 = 9.0908870101e-02f, aT5 = -7.6918758452e-02f,
                aT6 = 6.6610731184e-02f, aT7 = -5.8335702866e-02f, aT8 = 4.9768779427e-02f,
                aT9 = -3.6531571299e-02f, aT10 = 1.6285819933e-02f;
    const float pi    = 3.1415927410e+00f;
    const float pi_lo = -8.7422776573e-08f;
    const float pio2  = 1.5707963705e+00f;

    int hx = __float_as_int(gx), hy = __float_as_int(gy);
    int ix = hx & 0x7fffffff,   iy = hy & 0x7fffffff;
    int m  = ((hy >> 31) & 1) | ((hx >> 30) & 2);

    float q  = fabsf(gy / gx);
    int   iq = __float_as_int(q);

    // atanf(q), q >= 0: id-class via selects, identical op sequences to fdlibm
    bool lt04375 = iq < 0x3ee00000;
    bool lt06875 = iq < 0x3f300000;
    bool lt11875 = iq < 0x3f980000;
    bool lt24375 = iq < 0x401c0000;

    float n0 = 2.0f * q - 1.0f, d0 = 2.0f + q;          // id 0
    float n1 = q - 1.0f,        d1 = q + 1.0f;          // id 1
    float n2 = q - 1.5f,        d2 = 1.0f + 1.5f * q;   // id 2
    float num = lt04375 ? q    : lt06875 ? n0 : lt11875 ? n1 : lt24375 ? n2 : -1.0f;
    float den = lt04375 ? 1.0f : lt06875 ? d0 : lt11875 ? d1 : lt24375 ? d2 : q;
    float hi  = lt06875 ? 4.6364760399e-01f : lt11875 ? 7.8539812565e-01f
              : lt24375 ? 9.8279368877e-01f : 1.5707962513e+00f;
    float lo  = lt06875 ? 5.0121582440e-09f : lt11875 ? 3.7748947079e-08f
              : lt24375 ? 3.4473217170e-08f : 7.5497894159e-08f;

    float a  = num / den;
    float z2 = a * a;
    float w2 = z2 * z2;
    float s1 = z2 * (aT0 + w2 * (aT2 + w2 * (aT4 + w2 * (aT6 + w2 * (aT8 + w2 * aT10)))));
    float s2 = w2 * (aT1 + w2 * (aT3 + w2 * (aT5 + w2 * (aT7 + w2 * aT9))));
    float S  = s1 + s2;
    float resm1 = a - a * S;                       // id == -1 (incl. tiny-q exactness)
    float resid = hi - ((a * S - lo) - a);         // id >= 0
    float zr = lt04375 ? resm1 : resid;
    // |q| >= 2^26 (incl inf/NaN-from-0/0): fdlibm atanf returns atanhi3+atanlo3
    zr = (iq >= 0x4c800000) ? (1.5707962513e+00f + 7.5497894159e-08f) : zr;

    // atan2 wrapper
    int  k    = (iy - ix) >> 23;
    bool kbig = k > 26;
    float z   = kbig ? (pio2 + 0.5f * pi_lo) : zr;
    z = (hx < 0 && k < -26) ? 0.0f : z;
    int mm = kbig ? (m & 1) : m;

    float w  = z - pi_lo;
    float r2 = pi - w;
    float r3 = w - pi;
    float res = (mm == 0) ? z : (mm == 1) ? -z : (mm == 2) ? r2 : r3;
    // x == +-0, y != 0  ->  +-pi/2   (pi_o_2 + tiny rounds to pi_o_2)
    res = (ix == 0) ? ((hy < 0) ? -pio2 : pio2) : res;
    // y == +-0 (checked first in fdlibm -> applied last here)
    float piy = (m == 2) ? pi : (m == 3) ? -pi : gy;
    res = (iy == 0) ? piy : res;

    float t = res + 3.14159274101257324f;
    float u = t / 6.28318548202514648f;
    u = u * 8.0f;
    return ((int)u) & 7;
}

__device__ __forceinline__ unsigned rne_bf16_bits(float f) {
    unsigned u = __float_as_uint(f);
    return (u + 0x7fffu + ((u >> 16) & 1u)) >> 16;
}

// ================= stage 1: per-pixel bins (branch-free) =================
__global__ __launch_bounds__(256)
void bin_kernel(const float* __restrict__ x, unsigned* __restrict__ pwg) {
    __shared__ float rs[3][260];
    const int w    = threadIdx.x;
    const int hrow = blockIdx.x;
    const int img  = blockIdx.y;    // b*64 + c
    const float* xim = x + ((size_t)img << 16);
    #pragma unroll
    for (int r = 0; r < 3; ++r) {
        int gh = hrow - 1 + r;
        float v = 0.f;
        if ((unsigned)gh < 256u) v = xim[(gh << 8) + w];
        rs[r][w + 1] = v;
        if (w == 0) { rs[r][0] = 0.f; rs[r][257] = 0.f; }
    }
    __syncthreads();
    int q; unsigned hv;
    {
#pragma clang fp contract(off)
        float a0 = rs[0][w], a1 = rs[0][w + 1], a2 = rs[0][w + 2];
        float m0 = rs[1][w],                    m2 = rs[1][w + 2];
        float z0 = rs[2][w], z1 = rs[2][w + 1], z2 = rs[2][w + 2];
        float gx = ((((a0 - a2) + 2.0f * m0) - 2.0f * m2) + z0) - z2;
        float gy = ((((a0 + 2.0f * a1) + a2) - z0) - 2.0f * z1) - z2;
        q  = bin8_bf(gy, gx);
        hv = rne_bf16_bits(rs[1][w + 1]);
    }
    pwg[((size_t)img << 16) + (hrow << 8) + w] = (hv << 16) | (unsigned)q;
}

// ================= stage 1b: weights -> [c][t10][o64][k8] bf16 =================
__global__ void prep_w2(const float* __restrict__ Wg, short* __restrict__ wsw) {
    int tid = blockIdx.x * 256 + threadIdx.x;
    if (tid >= 4096) return;
    int c = tid >> 6, o = tid & 63;
    for (int t = 0; t < 9; ++t)
        #pragma unroll
        for (int k = 0; k < 8; ++k)
            wsw[((((c * 10 + t) << 6) + o) << 3) + k] =
                (short)rne_bf16_bits(Wg[(((k << 6) + o) * 64 + c) * 9 + t]);
    #pragma unroll
    for (int k = 0; k < 8; ++k)
        wsw[((((c * 10 + 9) << 6) + o) << 3) + k] = 0;
}

// one-hot expansion of packed (bf16<<16|q) into 8 bf16 K-slots (4 words)
__device__ __forceinline__ void build_oh(unsigned pv, u32x4* dst) {
    unsigned q  = pv & 7u;
    unsigned hv = (q & 1u) ? (pv & 0xffff0000u) : (pv >> 16);
    unsigned s2 = q >> 1;
    u32x4 oh;
    oh.x = (s2 == 0u) ? hv : 0u;
    oh.y = (s2 == 1u) ? hv : 0u;
    oh.z = (s2 == 2u) ? hv : 0u;
    oh.w = (s2 == 3u) ? hv : 0u;
    *dst = oh;
}

// ================= stage 2: MFMA GEMM, staging interleaved =================
__global__ __launch_bounds__(256, 2)
void dirconv_mfma2(const unsigned* __restrict__ pwg,
                   const short*    __restrict__ wsw,
                   const float*    __restrict__ bg,
                   float*          __restrict__ out) {
    __shared__ u32x4 pwx[2][648];   // 18 rows x 36 pitch (34 used): per-pixel one-hot
    __shared__ u32x4 wl2[2][640];   // [t10][o64]: A fragments, lane-contiguous
    __shared__ float bsum[64];

    const int tid  = threadIdx.x;
    const int wave = tid >> 6;
    const int lane = tid & 63;
    const int h    = lane >> 5;
    const int l31  = lane & 31;
    const int bb   = blockIdx.z;
    const int h0   = blockIdx.y * TH;
    const int w0c  = blockIdx.x * TW;

    if (tid < 64) {
        float s = 0.f;
        #pragma unroll
        for (int k = 0; k < 8; ++k) s += bg[k * 64 + tid];
        bsum[tid] = s;
    }

    f32x16 acc[2][4];
    #pragma unroll
    for (int i = 0; i < 2; ++i)
        #pragma unroll
        for (int j = 0; j < 4; ++j)
            acc[i][j] = (f32x16)0.f;

    // per-lane tap geometry; t=9 pad -> A=0, read clamped
    int rro[5], c2o[5];
    #pragma unroll
    for (int s = 0; s < 5; ++s) {
        int t = 2 * s + h;
        int t3 = t / 3;
        rro[s] = (t <= 8) ? t3 : 0;
        c2o[s] = (t <= 8) ? (t - t3 * 3) : 0;
    }

    // ---- prologue: stage c = 0 into buffer 0 ----
    {
        const u32x4* wsrc = (const u32x4*)wsw;
        wl2[0][tid]       = wsrc[tid];
        wl2[0][tid + 256] = wsrc[tid + 256];
        if (tid < 128) wl2[0][tid + 512] = wsrc[tid + 512];
        const unsigned* pimg = pwg + ((size_t)(bb * 64) << 16);
        #pragma unroll
        for (int rd = 0; rd < 3; ++rd) {
            int idx = tid + rd * 256;
            if (idx < 612) {
                int r = idx / 34, cc2 = idx - r * 34;
                int gh = h0 + r - 1, gw = w0c + cc2 - 1;
                unsigned pv = 0;
                if ((unsigned)gh < 256u && (unsigned)gw < 256u)
                    pv = pimg[(gh << 8) + gw];
                build_oh(pv, &pwx[0][r * 36 + cc2]);
            }
        }
    }
    __syncthreads();

    for (int c = 0; c < 64; ++c) {
        const int cb = c & 1, nb = cb ^ 1;
        u32x4 wv0 = (u32x4)0u, wv1 = (u32x4)0u, wv2 = (u32x4)0u;
        unsigned pv0 = 0, pv1 = 0, pv2 = 0;
        const bool more = (c < 63);

        if (more) {   // issue next-channel loads first
            const u32x4* wsrc = (const u32x4*)(wsw + (size_t)(c + 1) * 5120);
            wv0 = wsrc[tid];
            wv1 = wsrc[tid + 256];
            if (tid < 128) wv2 = wsrc[tid + 512];
            const unsigned* pimg = pwg + ((size_t)(bb * 64 + c + 1) << 16);
            {   int idx = tid;       int r = idx / 34, cc2 = idx - r * 34;
                int gh = h0 + r - 1, gw = w0c + cc2 - 1;
                if ((unsigned)gh < 256u && (unsigned)gw < 256u) pv0 = pimg[(gh << 8) + gw]; }
            {   int idx = tid + 256; int r = idx / 34, cc2 = idx - r * 34;
                int gh = h0 + r - 1, gw = w0c + cc2 - 1;
                if ((unsigned)gh < 256u && (unsigned)gw < 256u) pv1 = pimg[(gh << 8) + gw]; }
            if (tid < 100) {
                int idx = tid + 512; int r = idx / 34, cc2 = idx - r * 34;
                int gh = h0 + r - 1, gw = w0c + cc2 - 1;
                if ((unsigned)gh < 256u && (unsigned)gw < 256u) pv2 = pimg[(gh << 8) + gw]; }
        }

        const u32x4* pb = &pwx[cb][0];
        const u32x4* wb = &wl2[cb][0];
        auto mfma_step = [&](int s) {
            const int t = 2 * s + h;
            short8 a0 = __builtin_bit_cast(short8, wb[t * 64 + l31]);
            short8 a1 = __builtin_bit_cast(short8, wb[t * 64 + 32 + l31]);
            #pragma unroll
            for (int nf = 0; nf < 4; ++nf) {
                int py = wave * 4 + nf;
                short8 bf = __builtin_bit_cast(short8,
                                pb[(py + rro[s]) * 36 + l31 + c2o[s]]);
                acc[0][nf] = __builtin_amdgcn_mfma_f32_32x32x16_bf16(a0, bf, acc[0][nf], 0, 0, 0);
                acc[1][nf] = __builtin_amdgcn_mfma_f32_32x32x16_bf16(a1, bf, acc[1][nf], 0, 0, 0);
            }
        };

        // interleave: MFMA clusters | staging-write chunks (to the other buffer)
        __builtin_amdgcn_s_setprio(1);
        mfma_step(0);
        mfma_step(1);
        __builtin_amdgcn_s_setprio(0);
        if (more) {
            wl2[nb][tid]       = wv0;
            wl2[nb][tid + 256] = wv1;
            if (tid < 128) wl2[nb][tid + 512] = wv2;
        }
        __builtin_amdgcn_s_setprio(1);
        mfma_step(2);
        __builtin_amdgcn_s_setprio(0);
        if (more) {
            {   int idx = tid;       int r = idx / 34, cc2 = idx - r * 34;
                build_oh(pv0, &pwx[nb][r * 36 + cc2]); }
            {   int idx = tid + 256; int r = idx / 34, cc2 = idx - r * 34;
                build_oh(pv1, &pwx[nb][r * 36 + cc2]); }
        }
        __builtin_amdgcn_s_setprio(1);
        mfma_step(3);
        __builtin_amdgcn_s_setprio(0);
        if (more && tid < 100) {
            int idx = tid + 512; int r = idx / 34, cc2 = idx - r * 34;
            build_oh(pv2, &pwx[nb][r * 36 + cc2]);
        }
        __builtin_amdgcn_s_setprio(1);
        mfma_step(4);
        __builtin_amdgcn_s_setprio(0);
        __syncthreads();
    }

    // ---- epilogue: C/D layout col=lane&31 (pixel), row=(reg&3)+8*(reg>>2)+4*(lane>>5) (o) ----
    float* ob = out + ((size_t)bb << 22);
    #pragma unroll
    for (int mf = 0; mf < 2; ++mf)
        #pragma unroll
        for (int nf = 0; nf < 4; ++nf) {
            int py = wave * 4 + nf;
            #pragma unroll
            for (int reg = 0; reg < 16; ++reg) {
                int o = mf * 32 + (reg & 3) + 8 * (reg >> 2) + 4 * h;
                ob[((size_t)o << 16) + ((h0 + py) << 8) + (w0c + l31)] =
                    (acc[mf][nf][reg] + bsum[o]) * 0.125f;
            }
        }
}

// ================= fallback: fused kernel (branchy fdlibm, proven) =================
__global__ __launch_bounds__(256, 2)
void dirconv_fb(const float* __restrict__ x,
                const float* __restrict__ Wg,
                const float* __restrict__ bg,
                float* __restrict__ out) {
    __shared__ float    xs[20 * 37];
    __shared__ unsigned pw[18 * 36];
    __shared__ short    wl[64][128];
    __shared__ float    bsum[64];

    const int tid  = threadIdx.x;
    const int wave = tid >> 6;
    const int lane = tid & 63;
    const int h    = lane >> 5;
    const int l31  = lane & 31;
    const int bb   = blockIdx.z;
    const int h0   = blockIdx.y * TH;
    const int w0   = blockIdx.x * TW;

    if (tid < 64) {
        float s = 0.f;
        #pragma unroll
        for (int k = 0; k < 8; ++k) s += bg[k * 64 + tid];
        bsum[tid] = s;
    }

    f32x16 acc[2][4];
    #pragma unroll
    for (int i = 0; i < 2; ++i)
        #pragma unroll
        for (int j = 0; j < 4; ++j)
            acc[i][j] = (f32x16)0.f;

    const int swz0 = l31 & 7;

    for (int c = 0; c < 64; ++c) {
        __syncthreads();
        const float* xc = x + ((size_t)(bb * 64 + c) << 16);
        for (int idx = tid; idx < 720; idx += 256) {
            int r = idx / 36, cc = idx - r * 36;
            int gh = h0 + r - 2, gw = w0 + cc - 2;
            float v = 0.f;
            if ((unsigned)gh < 256u && (unsigned)gw < 256u)
                v = xc[(gh << 8) + gw];
            xs[r * 37 + cc] = v;
        }
        for (int pair = tid; pair < 512; pair += 256) {
            int k = pair >> 6, o = pair & 63;
            const float* g = Wg + ((size_t)((k << 6) + o) * 64 + c) * 9;
            #pragma unroll
            for (int t = 0; t < 9; ++t)
                wl[o][((t ^ (o & 7)) << 3) + k] = (short)rne_bf16_bits(g[t]);
        }
        if (tid < 64) {
            int o = tid;
            #pragma unroll
            for (int e = 0; e < 8; ++e) wl[o][((9 ^ (o & 7)) << 3) + e] = 0;
        }
        __syncthreads();

        for (int idx = tid; idx < 612; idx += 256) {
            int r = idx / 34, cc = idx - r * 34;
            const float* p0 = &xs[r * 37 + cc];
            int q; unsigned hv;
            {
#pragma clang fp contract(off)
                float a0 = p0[0],  a1 = p0[1],  a2 = p0[2];
                float m0 = p0[37],              m2 = p0[39];
                float z0 = p0[74], z1 = p0[75], z2 = p0[76];
                float gx = ((((a0 - a2) + 2.0f * m0) - 2.0f * m2) + z0) - z2;
                float gy = ((((a0 + 2.0f * a1) + a2) - z0) - 2.0f * z1) - z2;
                q  = bin8(gy, gx);
                hv = rne_bf16_bits(p0[38]);
            }
            pw[r * 36 + cc] = (hv << 16) | (unsigned)q;
        }
        __syncthreads();

        #pragma unroll
        for (int s = 0; s < 5; ++s) {
            const int t = 2 * s + h;
            short8 a0 = *(const short8*)&wl[l31     ][(t ^ swz0) << 3];
            short8 a1 = *(const short8*)&wl[32 + l31][(t ^ swz0) << 3];
            const int t3 = t / 3;
            const int dy = t3 - 1, dx = t - t3 * 3 - 1;
            const bool val = (t <= 8);
            #pragma unroll
            for (int nf = 0; nf < 4; ++nf) {
                int py = wave * 4 + nf;
                int rr = val ? (py + 1 + dy) : 0;
                int c2 = val ? (l31 + 1 + dx) : 0;
                unsigned pv = pw[rr * 36 + c2];
                pv = val ? pv : 0u;
                unsigned q   = pv & 7u;
                unsigned hhi = pv & 0xffff0000u;
                unsigned hlo = pv >> 16;
                u32x4 bw;
                bw.x = (q == 0u ? hlo : 0u) | (q == 1u ? hhi : 0u);
                bw.y = (q == 2u ? hlo : 0u) | (q == 3u ? hhi : 0u);
                bw.z = (q == 4u ? hlo : 0u) | (q == 5u ? hhi : 0u);
                bw.w = (q == 6u ? hlo : 0u) | (q == 7u ? hhi : 0u);
                short8 bf = __builtin_bit_cast(short8, bw);
                acc[0][nf] = __builtin_amdgcn_mfma_f32_32x32x16_bf16(a0, bf, acc[0][nf], 0, 0, 0);
                acc[1][nf] = __builtin_amdgcn_mfma_f32_32x32x16_bf16(a1, bf, acc[1][nf], 0, 0, 0);
            }
        }
    }

    float* ob = out + ((size_t)bb << 22);
    #pragma unroll
    for (int mf = 0; mf < 2; ++mf)
        #pragma unroll
        for (int nf = 0; nf < 4; ++nf) {
            int py = wave * 4 + nf;
            #pragma unroll
            for (int reg = 0; reg < 16; ++reg) {
                int o = mf * 32 + (reg & 3) + 8 * (reg >> 2) + 4 * h;
                ob[((size_t)o << 16) + ((h0 + py) << 8) + (w0 + l31)] =
                    (acc[mf][nf][reg] + bsum[o]) * 0.125f;
            }
        }
}

extern "C" void kernel_launch(void* const* d_in, const int* in_sizes, int n_in,
                              void* d_out, int out_size, void* d_ws, size_t ws_size,
                              hipStream_t stream) {
    const float* x  = (const float*)d_in[0];
    const float* Wg = (const float*)d_in[1];
    const float* bg = (const float*)d_in[2];
    float* out = (float*)d_out;

    dim3 grid(256 / TW, 256 / TH, 8);   // (8, 16, 8) = 1024 blocks
    dim3 block(256);

    const size_t pw_bytes   = (size_t)8 * 64 * 256 * 256 * 4;   // 134,217,728
    const size_t wsw2_bytes = (size_t)64 * 10 * 64 * 8 * 2;     // 655,360

    if (ws_size >= pw_bytes + wsw2_bytes) {
        unsigned* pwg = (unsigned*)d_ws;
        short*    wsw = (short*)((char*)d_ws + pw_bytes);
        bin_kernel<<<dim3(256, 512, 1), 256, 0, stream>>>(x, pwg);
        prep_w2<<<16, 256, 0, stream>>>(Wg, wsw);
        dirconv_mfma2<<<grid, block, 0, stream>>>(pwg, wsw, bg, out);
    } else {
        dirconv_fb<<<grid, block, 0, stream>>>(x, Wg, bg, out);
    }
}